// Round 20
// baseline (862.261 us; speedup 1.0000x reference)
//
#include <hip/hip_runtime.h>
#include <hip/hip_bf16.h>

typedef __hip_bfloat16 bf16;

#define BB 32
#define NN 50
#define DIN 2048
#define DD 512
#define PD 64
#define FF 80
#define GG 592
#define BN (BB*NN)      // 1600

// ---------------- ws layout (f32 words) ----------------
#define O_FLAG  0
#define O_MF    16
#define O_SS    1616
#define O_SO    3216
#define O_PS    4816
#define O_FS    107216
#define O_FO    235216
#define O_RL    363216
#define O_AH    491216
#define O_AN    571216
#define O_T     651216
#define O_X1    1598416
#define O_X2    2545616
#define O_WPRE  3364816
#define O_BPRE  4413392
#define O_GPRE  4413904
#define O_EPRE  4414416
#define O_WSUBJ 4414928
#define O_BSUBJ 4677072
#define O_WOBJ  4677584
#define O_BOBJ  4939728
#define O_WPS1  4940240
#define O_BPS1  4940752
#define O_GPS   4940816
#define O_EPS   4940880
#define O_WPS2  4940944
#define O_BPS2  4945040
#define O_WPR1  4945104
#define O_BPR1  4945616
#define O_GPR   4945680
#define O_EPR   4945744
#define O_WPR2  4945808
#define O_BPR2  4949904
#define O_WRS   4949968
#define O_BRS   4950544
#define O_WRF   4950560
#define O_BRF   4996640
#define O_WG1   4996736
#define O_BG1   5347200
#define O_WG2   5347792
#define O_BG2   5650896
#define O_WG3   5651408
#define O_BG3   5913552
// end 5,914,064 words = 23.7 MB

__device__ __forceinline__ float b2f(bf16 x){ return __bfloat162float(x); }

// Load logical f32 element i of an input buffer (bf16-pair reconstruction when F=1).
__device__ __forceinline__ float LDI(const bf16* p, size_t i, int f32m){
    if(f32m){
        bf16 a=p[2*i], b=p[2*i+1];
        unsigned short lo,hi;
        __builtin_memcpy(&lo,&a,2); __builtin_memcpy(&hi,&b,2);
        unsigned v=((unsigned)hi<<16)|(unsigned)lo;
        float f; __builtin_memcpy(&f,&v,4);
        return f;
    }
    return __bfloat162float(p[i]);
}

// ---------------- flag ----------------
__global__ void k_flag(const bf16* __restrict__ images, float* __restrict__ ws){
    __shared__ int cnt;
    if(threadIdx.x==0) cnt=0;
    __syncthreads();
    bf16 h=images[2*threadIdx.x];
    unsigned short u; __builtin_memcpy(&u,&h,2);
    unsigned e=(u>>7)&0xFF;
    int sane=((u&0x7FFF)==0 || (e>=0x70&&e<=0x85))?1:0;
    atomicAdd(&cnt,sane);
    __syncthreads();
    if(threadIdx.x==0) ws[O_FLAG]=(cnt<48)?1.f:0.f;
}

// ---------------- kw: convert all weights to f32 in ws ----------------
__device__ __forceinline__ void conv(const bf16* s, float* d, int n, int F, int i0, int st){
    for(int g=i0; g<n; g+=st) d[g]=LDI(s,(size_t)g,F);
}
__global__ void kw(const bf16* p0,const bf16* p1,const bf16* p2,const bf16* p3,
                   const bf16* p4,const bf16* p5,const bf16* p6,const bf16* p7,
                   const bf16* p8,const bf16* p9,const bf16* p10,const bf16* p11,
                   const bf16* p12,const bf16* p13,const bf16* p14,const bf16* p15,
                   const bf16* p16,const bf16* p17,const bf16* p18,const bf16* p19,
                   const bf16* p20,const bf16* p21,const bf16* p22,const bf16* p23,
                   const bf16* p24,const bf16* p25,const bf16* p26,const bf16* p27,
                   const bf16* p28,const bf16* p29, float* __restrict__ ws){
    int F=ws[O_FLAG]>0.5f;
    int i0=blockIdx.x*256+threadIdx.x, st=gridDim.x*256;
    conv(p0, ws+O_WPRE, 1048576,F,i0,st);
    conv(p1, ws+O_BPRE, 512,F,i0,st);
    conv(p2, ws+O_GPRE, 512,F,i0,st);
    conv(p3, ws+O_EPRE, 512,F,i0,st);
    conv(p4, ws+O_WSUBJ,262144,F,i0,st);
    conv(p5, ws+O_BSUBJ,512,F,i0,st);
    conv(p6, ws+O_WOBJ, 262144,F,i0,st);
    conv(p7, ws+O_BOBJ, 512,F,i0,st);
    conv(p8, ws+O_WPS1, 512,F,i0,st);
    conv(p9, ws+O_BPS1, 64,F,i0,st);
    conv(p10,ws+O_GPS,  64,F,i0,st);
    conv(p11,ws+O_EPS,  64,F,i0,st);
    conv(p12,ws+O_WPS2, 4096,F,i0,st);
    conv(p13,ws+O_BPS2, 64,F,i0,st);
    conv(p14,ws+O_WPR1, 512,F,i0,st);
    conv(p15,ws+O_BPR1, 64,F,i0,st);
    conv(p16,ws+O_GPR,  64,F,i0,st);
    conv(p17,ws+O_EPR,  64,F,i0,st);
    conv(p18,ws+O_WPR2, 4096,F,i0,st);
    conv(p19,ws+O_BPR2, 64,F,i0,st);
    conv(p20,ws+O_WRS,  576,F,i0,st);
    conv(p21,ws+O_BRS,  1,F,i0,st);
    conv(p22,ws+O_WRF,  46080,F,i0,st);
    conv(p23,ws+O_BRF,  80,F,i0,st);
    conv(p24,ws+O_WG1,  350464,F,i0,st);
    conv(p25,ws+O_BG1,  592,F,i0,st);
    conv(p26,ws+O_WG2,  303104,F,i0,st);
    conv(p27,ws+O_BG2,  512,F,i0,st);
    conv(p28,ws+O_WG3,  262144,F,i0,st);
    conv(p29,ws+O_BG3,  512,F,i0,st);
}

// ---------------- k_pre: 4 rows/block, 512 threads (1 col/thread) ----------------
__global__ void k_pre(const bf16* __restrict__ images, float* __restrict__ ws,
                      float* __restrict__ out){
    __shared__ float a[4*DIN];       // 32KB; later reused for xs(4)|xo(4) rows
    __shared__ float xr[4*DD];       // 8KB
    __shared__ float red[512];
    int blk=blockIdx.x, t=threadIdx.x;
    int r0=blk*4;
    int F=ws[O_FLAG]>0.5f;
    const float* wPre=ws+O_WPRE; const float* bPre=ws+O_BPRE;
    const float* gPre=ws+O_GPRE; const float* ePre=ws+O_EPRE;
    const float* wSu=ws+O_WSUBJ; const float* bSu=ws+O_BSUBJ;
    const float* wOb=ws+O_WOBJ;  const float* bOb=ws+O_BOBJ;
    const float* wRs=ws+O_WRS;   const float* wRf=ws+O_WRF;

    float psum[4]={0.f,0.f,0.f,0.f};
    for(int idx=t; idx<4*DIN; idx+=512){
        float v=LDI(images,(size_t)r0*DIN+idx,F);
        a[idx]=v;
        psum[idx>>11]+=v;
    }
    float mrow[4];
    for(int row=0;row<4;row++){
        red[t]=psum[row]; __syncthreads();
        for(int o=256;o>0;o>>=1){ if(t<o) red[t]+=red[t+o]; __syncthreads(); }
        mrow[row]=(red[0]!=0.f)?1.f:0.f;
        __syncthreads();
    }
    if(t<4){
        ws[O_MF+r0+t]=mrow[t];
        out[(size_t)BB*2*NN*DD + r0 + t]=1.f-mrow[t];
    }
    int c=t;   // one column per thread
    float acc[4]={0.f,0.f,0.f,0.f};
    for(int k=0;k<DIN;k++){
        float w0=wPre[(size_t)k*DD+c];
        #pragma unroll
        for(int row=0;row<4;row++) acc[row]+=a[row*DIN+k]*w0;
    }
    float y[4];
    #pragma unroll
    for(int row=0;row<4;row++) y[row]=fmaxf(acc[row]+bPre[c],0.f);
    for(int row=0;row<4;row++){
        __syncthreads();
        red[t]=y[row]; __syncthreads();
        for(int o=256;o>0;o>>=1){ if(t<o) red[t]+=red[t+o]; __syncthreads(); }
        float mean=red[0]/DD;
        __syncthreads();
        float d=y[row]-mean;
        red[t]=d*d; __syncthreads();
        for(int o=256;o>0;o>>=1){ if(t<o) red[t]+=red[t+o]; __syncthreads(); }
        float rstd=rsqrtf(red[0]/DD+1e-5f);
        float xv=d*rstd*gPre[c]+ePre[c];
        xr[row*DD+c]=xv;
        int r=r0+row;
        size_t ob=((size_t)(r/NN)*2)*NN*DD+(size_t)(r%NN)*DD;
        out[ob+c]=xv;
    }
    __syncthreads();
    // subj/obj GEMM (4 rows)
    float su[4]={0.f,0.f,0.f,0.f}, oo[4]={0.f,0.f,0.f,0.f};
    for(int k=0;k<DD;k++){
        float ws0=wSu[(size_t)k*DD+c];
        float wo0=wOb[(size_t)k*DD+c];
        #pragma unroll
        for(int row=0;row<4;row++){
            float v=xr[row*DD+k];
            su[row]+=v*ws0; oo[row]+=v*wo0;
        }
    }
    __syncthreads();     // image data in a[] dead
    #pragma unroll
    for(int row=0;row<4;row++){
        a[row*DD+c]     =fmaxf(su[row]+bSu[c],0.f)*mrow[row];   // xs
        a[4*DD+row*DD+c]=fmaxf(oo[row]+bOb[c],0.f)*mrow[row];   // xo
    }
    __syncthreads();
    // ss/so: 8 waves — waves 0-3: ss rows 0-3; waves 4-7: so rows 0-3
    int wv=t>>6, ln=t&63;
    int rw=wv&3;
    const float* src=(wv<4)? (a+rw*DD) : (a+4*DD+rw*DD);
    float pp=0.f;
    for(int k=ln;k<DD;k+=64) pp+=src[k]*wRs[k];
    for(int m=32;m>0;m>>=1) pp+=__shfl_xor(pp,m,64);
    if(ln==0) ws[(wv<4?O_SS:O_SO)+r0+rw]=pp;
    // Fs/Fo: 8 combos x 80 outputs = 640 items over 2 passes
    for(int pass=0;pass<2;pass++){
        int item=pass*512+t;
        if(item<640){
            int cb=item/80, f=item-cb*80;
            int row=cb>>1, sel=cb&1;
            const float* xv=a + sel*4*DD + row*DD;
            float accf=0.f;
            for(int k=0;k<DD;k++) accf+=xv[k]*wRf[(size_t)k*FF+f];
            ws[(sel? O_FO:O_FS)+(size_t)(r0+row)*FF+f]=accf;
        }
    }
}

// ---------------- k_pos_self ----------------
__global__ void k_pos_self(const bf16* __restrict__ sb, float* __restrict__ ws){
    __shared__ float h[PD];
    __shared__ float stat[2];
    int r=blockIdx.x, t=threadIdx.x;
    int F=ws[O_FLAG]>0.5f;
    const float* w1=ws+O_WPS1;
    float acc=0.f;
    for(int q=0;q<8;q++) acc+=LDI(sb,(size_t)r*8+q,F)*w1[q*PD+t];
    acc=fmaxf(acc+ws[O_BPS1+t],0.f);
    h[t]=acc; __syncthreads();
    if(t==0){
        float sm=0; for(int k=0;k<PD;k++) sm+=h[k];
        float mean=sm/PD;
        float v=0; for(int k=0;k<PD;k++){float d=h[k]-mean; v+=d*d;}
        stat[0]=mean; stat[1]=rsqrtf(v/PD+1e-5f);
    }
    __syncthreads();
    float hn=(acc-stat[0])*stat[1]*ws[O_GPS+t]+ws[O_EPS+t];
    h[t]=hn; __syncthreads();
    float a2=0.f;
    const float* w2=ws+O_WPS2;
    for(int k=0;k<PD;k++) a2+=h[k]*w2[k*PD+t];
    ws[O_PS+(size_t)r*PD+t]=fmaxf(a2+ws[O_BPS2+t],0.f)*ws[O_MF+r];
}

// ---------------- k_pair: wave-parallel pair loop ----------------
// Shuffle-based GEMVs; rfw2 staged as bf16 (feat path only — logits stay f32)
// to cut LDS 42->31.5 KB and admit 4 blocks/CU.
#define LW1  0          // 512  (w1 8x64)
#define LB1  512        // 64
#define LG_  576        // 64
#define LBE  640        // 64
#define LW2  704        // 4096 (w2 64x64)
#define LB2  4800       // 64
#define LRST 4864       // 64  (rs_w[512:576])
#define LRFB 4928       // 80  (rf_b)
#define LTOT 5008       // f32 words (19.6 KB)
#define NRF  5120       // bf16 rfw2 table (10 KB)

__global__ void __launch_bounds__(256,2) k_pair(const bf16* __restrict__ bbox,
                                                float* __restrict__ ws){
    __shared__ float L[LTOT];
    __shared__ bf16 Lrf[NRF];
    __shared__ float mrg[8];         // per-wave m,l
    __shared__ float macc[4*FF];     // per-wave acc
    int t=threadIdx.x;
    int wv=t>>6, ln=t&63;
    int r=blockIdx.x;
    int b=r/NN, i=r%NN;
    int F=ws[O_FLAG]>0.5f;
    // stage weights once per block
    for(int idx=t; idx<LTOT; idx+=256){
        float v;
        if(idx<LB1)       v=ws[O_WPR1+idx];
        else if(idx<LG_)  v=ws[O_BPR1+idx-LB1];
        else if(idx<LBE)  v=ws[O_GPR+idx-LG_];
        else if(idx<LW2)  v=ws[O_EPR+idx-LBE];
        else if(idx<LB2)  v=ws[O_WPR2+idx-LW2];
        else if(idx<LRST) v=ws[O_BPR2+idx-LB2];
        else if(idx<LRFB) v=ws[O_WRS+512+idx-LRST];
        else              v=ws[O_BRF+idx-LRFB];
        L[idx]=v;
    }
    for(int idx=t; idx<NRF; idx+=256)
        Lrf[idx]=__float2bfloat16(ws[O_WRF+(size_t)512*FF+idx]);
    float mi=ws[O_MF+r];
    float rsbv=ws[O_BRS];
    float ss_r=ws[O_SS+r];
    __syncthreads();
    float m_run=-1e30f, l_run=0.f;
    float acc0=0.f, acc1=0.f;
    int f1=64+(ln&15);
    for(int j=wv; j<NN; j+=4){
        float mj=ws[O_MF+b*NN+j];
        float prv;
        if(j==i){
            prv=ws[O_PS+(size_t)r*PD+ln];
        } else {
            size_t bbase=((size_t)r*NN+j)*8;
            float a=0.f;
            #pragma unroll
            for(int q=0;q<8;q++) a+=LDI(bbox,bbase+q,F)*L[LW1+q*PD+ln];
            float h1=fmaxf(a+L[LB1+ln],0.f);
            float sm=h1;
            for(int m=32;m>0;m>>=1) sm+=__shfl_xor(sm,m,64);
            float mean=sm*(1.f/64.f);
            float d=h1-mean;
            float vv=d*d;
            for(int m=32;m>0;m>>=1) vv+=__shfl_xor(vv,m,64);
            float rstd=rsqrtf(vv*(1.f/64.f)+1e-5f);
            float lnv=d*rstd*L[LG_+ln]+L[LBE+ln];
            float a2=0.f;
            for(int k=0;k<PD;k++) a2+=__shfl(lnv,k,64)*L[LW2+k*PD+ln];
            prv=fmaxf(a2+L[LB2+ln],0.f)*mi*mj;
        }
        // logit
        float lp=prv*L[LRST+ln];
        for(int m=32;m>0;m>>=1) lp+=__shfl_xor(lp,m,64);
        float base=(j==i)? ss_r : ws[O_SO+b*NN+j];
        float lgj=mi*base+lp+rsbv;
        if(ln==0) ws[O_AH+(size_t)r*NN+j]=((j==i)||(lgj>0.f&&mi>0.5f&&mj>0.5f))?1.f:0.f;
        float lgm=(mi>0.5f&&mj>0.5f)? lgj : -1e9f;
        float mnew=fmaxf(m_run,lgm);
        float scl=__expf(m_run-mnew);
        float wj=__expf(lgm-mnew);
        l_run=l_run*scl+wj; m_run=mnew;
        // feat dots via shuffle broadcast of prv
        float fp0=0.f, fp1=0.f;
        for(int k=0;k<PD;k++){
            float pk=__shfl(prv,k,64);
            fp0+=pk*b2f(Lrf[k*FF+ln]);
            fp1+=pk*b2f(Lrf[k*FF+f1]);
        }
        float fb0=(j==i)? ws[O_FS+(size_t)r*FF+ln] : ws[O_FO+(size_t)(b*NN+j)*FF+ln];
        float fd0=fmaxf(mi*fb0+fp0+L[LRFB+ln],0.f);
        acc0=acc0*scl+wj*fd0;
        if(ln<16){
            float fb1=(j==i)? ws[O_FS+(size_t)r*FF+f1] : ws[O_FO+(size_t)(b*NN+j)*FF+f1];
            float fd1=fmaxf(mi*fb1+fp1+L[LRFB+f1],0.f);
            acc1=acc1*scl+wj*fd1;
        }
    }
    if(ln==0){ mrg[wv]=m_run; mrg[4+wv]=l_run; }
    macc[wv*FF+ln]=acc0;
    if(ln<16) macc[wv*FF+64+ln]=acc1;
    __syncthreads();
    if(t<FF){
        float mstar=fmaxf(fmaxf(mrg[0],mrg[1]),fmaxf(mrg[2],mrg[3]));
        float lstar=0.f, num=0.f;
        #pragma unroll
        for(int w=0;w<4;w++){
            float e=__expf(mrg[w]-mstar);
            lstar+=mrg[4+w]*e;
            num+=macc[w*FF+t]*e;
        }
        ws[O_RL+(size_t)r*FF+t]=num/lstar*mi;
    }
}

// ---------------- k_adj ----------------
__global__ void k_adj(float* __restrict__ ws){
    __shared__ float Af[NN*NN];
    __shared__ float dinv[NN];
    int b=blockIdx.x, t=threadIdx.x;
    for(int idx=t; idx<NN*NN; idx+=256) Af[idx]=(ws[O_AH+(size_t)b*NN*NN+idx]>0.5f)?1.f:0.f;
    __syncthreads();
    if(t<NN){
        float dg=0.f;
        for(int i=0;i<NN;i++) dg+=Af[i*NN+t];
        dinv[t]=rsqrtf(dg);
    }
    __syncthreads();
    for(int idx=t; idx<NN*NN; idx+=256){
        int i=idx/NN, j=idx%NN;
        ws[O_AN+(size_t)b*NN*NN+idx]=Af[idx]*dinv[i]*dinv[j];
    }
}

// ---------------- kt: T = X @ W (10-row x 256-col register tiles) ----------------
__global__ void kt(int mode, const float* __restrict__ out, const float* __restrict__ ws,
                   const float* __restrict__ W, float* __restrict__ T,
                   int K, int NCOL, int NTILE){
    __shared__ float xs[10*GG];
    int blk=blockIdx.x, t=threadIdx.x;
    int rg=blk/NTILE, tile=blk%NTILE;
    for(int idx=t; idx<10*K; idx+=256){
        int row=idx/K, k=idx-row*K;
        int gr=rg*10+row;
        float v;
        if(mode==0){
            int bb=gr/NN, ii=gr-bb*NN;
            if(k<DD) v=out[(size_t)(2*bb)*NN*DD+(size_t)ii*DD+k];
            else     v=ws[O_RL+(size_t)gr*FF+(k-DD)];
        } else if(mode==1) v=ws[O_X1+(size_t)gr*GG+k];
        else               v=ws[O_X2+(size_t)gr*DD+k];
        xs[row*K+k]=v;
    }
    __syncthreads();
    int c=tile*256+t;
    if(c>=NCOL) return;
    float acc[10];
    #pragma unroll
    for(int u=0;u<10;u++) acc[u]=0.f;
    for(int k=0;k<K;k++){
        float w=W[(size_t)k*NCOL+c];
        #pragma unroll
        for(int u=0;u<10;u++) acc[u]+=xs[u*K+k]*w;
    }
    int gr0=rg*10;
    #pragma unroll
    for(int u=0;u<10;u++) T[(size_t)(gr0+u)*NCOL+c]=acc[u];
}

// ---------------- ka: aggregation ----------------
__global__ void ka(int mode, float* __restrict__ ws, const float* __restrict__ bias,
                   float* __restrict__ out, int NCOL){
    __shared__ float acol[NN];
    int rj=blockIdx.x, t=threadIdx.x;
    int b=rj/NN, j=rj-b*NN;
    if(t<NN) acol[t]=ws[O_AN+(size_t)b*NN*NN+t*NN+j];
    __syncthreads();
    const float* Tb=ws+O_T+(size_t)b*NN*NCOL;
    for(int c=t;c<NCOL;c+=256){
        float acc=0.f;
        for(int i2=0;i2<NN;i2++) acc+=acol[i2]*Tb[(size_t)i2*NCOL+c];
        float v=fmaxf(acc+bias[c],0.f);
        if(mode==2)      out[(size_t)(2*b+1)*NN*DD+(size_t)j*DD+c]=v;
        else if(mode==1) ws[O_X2+(size_t)rj*DD+c]=v;
        else             ws[O_X1+(size_t)rj*GG+c]=v;
    }
}

extern "C" void kernel_launch(void* const* d_in, const int* in_sizes, int n_in,
                              void* d_out, int out_size, void* d_ws, size_t ws_size,
                              hipStream_t stream) {
    const bf16* images  = (const bf16*)d_in[0];
    const bf16* selfbbox= (const bf16*)d_in[1];
    const bf16* bbox    = (const bf16*)d_in[2];

    float* out=(float*)d_out;
    float* ws =(float*)d_ws;

    k_flag<<<1,64,0,stream>>>(images, ws);
    kw<<<512,256,0,stream>>>((const bf16*)d_in[3],(const bf16*)d_in[4],(const bf16*)d_in[5],
                             (const bf16*)d_in[6],(const bf16*)d_in[7],(const bf16*)d_in[8],
                             (const bf16*)d_in[9],(const bf16*)d_in[10],(const bf16*)d_in[11],
                             (const bf16*)d_in[12],(const bf16*)d_in[13],(const bf16*)d_in[14],
                             (const bf16*)d_in[15],(const bf16*)d_in[16],(const bf16*)d_in[17],
                             (const bf16*)d_in[18],(const bf16*)d_in[19],(const bf16*)d_in[20],
                             (const bf16*)d_in[21],(const bf16*)d_in[22],(const bf16*)d_in[23],
                             (const bf16*)d_in[24],(const bf16*)d_in[25],(const bf16*)d_in[26],
                             (const bf16*)d_in[27],(const bf16*)d_in[28],(const bf16*)d_in[29],
                             (const bf16*)d_in[30],(const bf16*)d_in[31],(const bf16*)d_in[32],
                             ws);
    k_pre<<<BN/4,512,0,stream>>>(images, ws, out);
    k_pos_self<<<BN,PD,0,stream>>>(selfbbox, ws);
    k_pair<<<BN,256,0,stream>>>(bbox, ws);
    k_adj<<<BB,256,0,stream>>>(ws);

    kt<<<160*3,256,0,stream>>>(0, out, ws, ws+O_WG1, ws+O_T, GG, GG, 3);
    ka<<<BN,256,0,stream>>>(0, ws, ws+O_BG1, out, GG);
    kt<<<160*2,256,0,stream>>>(1, out, ws, ws+O_WG2, ws+O_T, GG, DD, 2);
    ka<<<BN,256,0,stream>>>(1, ws, ws+O_BG2, out, DD);
    kt<<<160*2,256,0,stream>>>(2, out, ws, ws+O_WG3, ws+O_T, DD, DD, 2);
    ka<<<BN,256,0,stream>>>(2, ws, ws+O_BG3, out, DD);
}

// Round 22
// 828.292 us; speedup vs baseline: 1.0410x; 1.0410x over previous
//
#include <hip/hip_runtime.h>
#include <hip/hip_bf16.h>

typedef __hip_bfloat16 bf16;

#define BB 32
#define NN 50
#define DIN 2048
#define DD 512
#define PD 64
#define FF 80
#define GG 592
#define BN (BB*NN)      // 1600

// ---------------- ws layout (f32 words) ----------------
#define O_FLAG  0
#define O_MF    16
#define O_SS    1616
#define O_SO    3216
#define O_PS    4816
#define O_FS    107216
#define O_FO    235216
#define O_RL    363216
#define O_AH    491216
#define O_AN    571216
#define O_T     651216
#define O_X1    1598416
#define O_X2    2545616
#define O_WPRE  3364816
#define O_BPRE  4413392
#define O_GPRE  4413904
#define O_EPRE  4414416
#define O_WSUBJ 4414928
#define O_BSUBJ 4677072
#define O_WOBJ  4677584
#define O_BOBJ  4939728
#define O_WPS1  4940240
#define O_BPS1  4940752
#define O_GPS   4940816
#define O_EPS   4940880
#define O_WPS2  4940944
#define O_BPS2  4945040
#define O_WPR1  4945104
#define O_BPR1  4945616
#define O_GPR   4945680
#define O_EPR   4945744
#define O_WPR2  4945808
#define O_BPR2  4949904
#define O_WRS   4949968
#define O_BRS   4950544
#define O_WRF   4950560
#define O_BRF   4996640
#define O_WG1   4996736
#define O_BG1   5347200
#define O_WG2   5347792
#define O_BG2   5650896
#define O_WG3   5651408
#define O_BG3   5913552
// end 5,914,064 words = 23.7 MB

__device__ __forceinline__ float b2f(bf16 x){ return __bfloat162float(x); }

// Load logical f32 element i of an input buffer (bf16-pair reconstruction when F=1).
__device__ __forceinline__ float LDI(const bf16* p, size_t i, int f32m){
    if(f32m){
        bf16 a=p[2*i], b=p[2*i+1];
        unsigned short lo,hi;
        __builtin_memcpy(&lo,&a,2); __builtin_memcpy(&hi,&b,2);
        unsigned v=((unsigned)hi<<16)|(unsigned)lo;
        float f; __builtin_memcpy(&f,&v,4);
        return f;
    }
    return __bfloat162float(p[i]);
}

// ---------------- flag ----------------
__global__ void k_flag(const bf16* __restrict__ images, float* __restrict__ ws){
    __shared__ int cnt;
    if(threadIdx.x==0) cnt=0;
    __syncthreads();
    bf16 h=images[2*threadIdx.x];
    unsigned short u; __builtin_memcpy(&u,&h,2);
    unsigned e=(u>>7)&0xFF;
    int sane=((u&0x7FFF)==0 || (e>=0x70&&e<=0x85))?1:0;
    atomicAdd(&cnt,sane);
    __syncthreads();
    if(threadIdx.x==0) ws[O_FLAG]=(cnt<48)?1.f:0.f;
}

// ---------------- kw: convert all weights to f32 in ws (NO quantization — R21 showed
// the weights are genuine f32; any logit-path rounding flips p>0.5 edges) ----------------
__device__ __forceinline__ void conv(const bf16* s, float* d, int n, int F, int i0, int st){
    for(int g=i0; g<n; g+=st) d[g]=LDI(s,(size_t)g,F);
}
__global__ void kw(const bf16* p0,const bf16* p1,const bf16* p2,const bf16* p3,
                   const bf16* p4,const bf16* p5,const bf16* p6,const bf16* p7,
                   const bf16* p8,const bf16* p9,const bf16* p10,const bf16* p11,
                   const bf16* p12,const bf16* p13,const bf16* p14,const bf16* p15,
                   const bf16* p16,const bf16* p17,const bf16* p18,const bf16* p19,
                   const bf16* p20,const bf16* p21,const bf16* p22,const bf16* p23,
                   const bf16* p24,const bf16* p25,const bf16* p26,const bf16* p27,
                   const bf16* p28,const bf16* p29, float* __restrict__ ws){
    int F=ws[O_FLAG]>0.5f;
    int i0=blockIdx.x*256+threadIdx.x, st=gridDim.x*256;
    conv(p0, ws+O_WPRE, 1048576,F,i0,st);
    conv(p1, ws+O_BPRE, 512,F,i0,st);
    conv(p2, ws+O_GPRE, 512,F,i0,st);
    conv(p3, ws+O_EPRE, 512,F,i0,st);
    conv(p4, ws+O_WSUBJ,262144,F,i0,st);
    conv(p5, ws+O_BSUBJ,512,F,i0,st);
    conv(p6, ws+O_WOBJ, 262144,F,i0,st);
    conv(p7, ws+O_BOBJ, 512,F,i0,st);
    conv(p8, ws+O_WPS1, 512,F,i0,st);
    conv(p9, ws+O_BPS1, 64,F,i0,st);
    conv(p10,ws+O_GPS,  64,F,i0,st);
    conv(p11,ws+O_EPS,  64,F,i0,st);
    conv(p12,ws+O_WPS2, 4096,F,i0,st);
    conv(p13,ws+O_BPS2, 64,F,i0,st);
    conv(p14,ws+O_WPR1, 512,F,i0,st);
    conv(p15,ws+O_BPR1, 64,F,i0,st);
    conv(p16,ws+O_GPR,  64,F,i0,st);
    conv(p17,ws+O_EPR,  64,F,i0,st);
    conv(p18,ws+O_WPR2, 4096,F,i0,st);
    conv(p19,ws+O_BPR2, 64,F,i0,st);
    conv(p20,ws+O_WRS,  576,F,i0,st);
    conv(p21,ws+O_BRS,  1,F,i0,st);
    conv(p22,ws+O_WRF,  46080,F,i0,st);
    conv(p23,ws+O_BRF,  80,F,i0,st);
    conv(p24,ws+O_WG1,  350464,F,i0,st);
    conv(p25,ws+O_BG1,  592,F,i0,st);
    conv(p26,ws+O_WG2,  303104,F,i0,st);
    conv(p27,ws+O_BG2,  512,F,i0,st);
    conv(p28,ws+O_WG3,  262144,F,i0,st);
    conv(p29,ws+O_BG3,  512,F,i0,st);
}

// ---------------- k_pre: 4 rows/block, 256 threads, unroll-8 register prefetch ----------------
__global__ void __launch_bounds__(256,3) k_pre(const bf16* __restrict__ images,
                                               float* __restrict__ ws,
                                               float* __restrict__ out){
    __shared__ float a[4*DIN];       // 32KB; later reused for xs(4)|xo(4) rows
    __shared__ float xr[4*DD];       // 8KB
    __shared__ float red[256];
    int blk=blockIdx.x, t=threadIdx.x;
    int r0=blk*4;
    int F=ws[O_FLAG]>0.5f;
    const float* wPre=ws+O_WPRE; const float* bPre=ws+O_BPRE;
    const float* gPre=ws+O_GPRE; const float* ePre=ws+O_EPRE;
    const float* wSu=ws+O_WSUBJ; const float* bSu=ws+O_BSUBJ;
    const float* wOb=ws+O_WOBJ;  const float* bOb=ws+O_BOBJ;
    const float* wRs=ws+O_WRS;   const float* wRf=ws+O_WRF;

    float psum[4]={0.f,0.f,0.f,0.f};
    for(int idx=t; idx<4*DIN; idx+=256){
        float v=LDI(images,(size_t)r0*DIN+idx,F);
        a[idx]=v;
        psum[idx>>11]+=v;
    }
    float mrow[4];
    for(int row=0;row<4;row++){
        red[t]=psum[row]; __syncthreads();
        for(int o=128;o>0;o>>=1){ if(t<o) red[t]+=red[t+o]; __syncthreads(); }
        mrow[row]=(red[0]!=0.f)?1.f:0.f;
        __syncthreads();
    }
    if(t<4){
        ws[O_MF+r0+t]=mrow[t];
        out[(size_t)BB*2*NN*DD + r0 + t]=1.f-mrow[t];
    }
    int c0=t, c1=t+256;
    float acc[4][2]={};
    for(int k0=0;k0<DIN;k0+=8){
        float w0v[8], w1v[8];
        #pragma unroll
        for(int u=0;u<8;u++){
            w0v[u]=wPre[(size_t)(k0+u)*DD+c0];
            w1v[u]=wPre[(size_t)(k0+u)*DD+c1];
        }
        #pragma unroll
        for(int u=0;u<8;u++){
            #pragma unroll
            for(int row=0;row<4;row++){
                float v=a[row*DIN+k0+u];
                acc[row][0]+=v*w0v[u]; acc[row][1]+=v*w1v[u];
            }
        }
    }
    float y[4][2];
    #pragma unroll
    for(int row=0;row<4;row++){
        y[row][0]=fmaxf(acc[row][0]+bPre[c0],0.f);
        y[row][1]=fmaxf(acc[row][1]+bPre[c1],0.f);
    }
    for(int row=0;row<4;row++){
        __syncthreads();
        red[t]=y[row][0]+y[row][1]; __syncthreads();
        for(int o=128;o>0;o>>=1){ if(t<o) red[t]+=red[t+o]; __syncthreads(); }
        float mean=red[0]/DD;
        __syncthreads();
        float d0=y[row][0]-mean, d1=y[row][1]-mean;
        red[t]=d0*d0+d1*d1; __syncthreads();
        for(int o=128;o>0;o>>=1){ if(t<o) red[t]+=red[t+o]; __syncthreads(); }
        float rstd=rsqrtf(red[0]/DD+1e-5f);
        float xv0=d0*rstd*gPre[c0]+ePre[c0];
        float xv1=d1*rstd*gPre[c1]+ePre[c1];
        xr[row*DD+c0]=xv0; xr[row*DD+c1]=xv1;
        int r=r0+row;
        size_t ob=((size_t)(r/NN)*2)*NN*DD+(size_t)(r%NN)*DD;
        out[ob+c0]=xv0; out[ob+c1]=xv1;
    }
    __syncthreads();
    // subj/obj GEMM (4 rows), unroll-8 prefetch
    float su[4][2]={}, oo[4][2]={};
    for(int k0=0;k0<DD;k0+=8){
        float ws0v[8], ws1v[8], wo0v[8], wo1v[8];
        #pragma unroll
        for(int u=0;u<8;u++){
            ws0v[u]=wSu[(size_t)(k0+u)*DD+c0]; ws1v[u]=wSu[(size_t)(k0+u)*DD+c1];
            wo0v[u]=wOb[(size_t)(k0+u)*DD+c0]; wo1v[u]=wOb[(size_t)(k0+u)*DD+c1];
        }
        #pragma unroll
        for(int u=0;u<8;u++){
            #pragma unroll
            for(int row=0;row<4;row++){
                float v=xr[row*DD+k0+u];
                su[row][0]+=v*ws0v[u]; su[row][1]+=v*ws1v[u];
                oo[row][0]+=v*wo0v[u]; oo[row][1]+=v*wo1v[u];
            }
        }
    }
    __syncthreads();     // image data in a[] dead
    #pragma unroll
    for(int row=0;row<4;row++){
        a[row*DD+c0]     =fmaxf(su[row][0]+bSu[c0],0.f)*mrow[row];   // xs
        a[row*DD+c1]     =fmaxf(su[row][1]+bSu[c1],0.f)*mrow[row];
        a[4*DD+row*DD+c0]=fmaxf(oo[row][0]+bOb[c0],0.f)*mrow[row];   // xo
        a[4*DD+row*DD+c1]=fmaxf(oo[row][1]+bOb[c1],0.f)*mrow[row];
    }
    __syncthreads();
    // ss/so: wave wv handles row wv
    int wv=t>>6, ln=t&63;
    float ps=0.f, po=0.f;
    for(int k=ln;k<DD;k+=64){ ps+=a[wv*DD+k]*wRs[k]; po+=a[4*DD+wv*DD+k]*wRs[k]; }
    for(int m=32;m>0;m>>=1){ ps+=__shfl_xor(ps,m,64); po+=__shfl_xor(po,m,64); }
    if(ln==0){ ws[O_SS+r0+wv]=ps; ws[O_SO+r0+wv]=po; }
    // Fs/Fo: 8 combos, 3 groups of 80 at a time
    for(int pass=0;pass<3;pass++){
        int cb=pass*3+(t/80);
        if(t<240 && cb<8){
            int row=cb>>1, sel=cb&1;
            int f=t%80;
            const float* xv=a + sel*4*DD + row*DD;
            float accf=0.f;
            for(int k=0;k<DD;k++) accf+=xv[k]*wRf[(size_t)k*FF+f];
            ws[(sel? O_FO:O_FS)+(size_t)(r0+row)*FF+f]=accf;
        }
    }
}

// ---------------- k_pos_self ----------------
__global__ void k_pos_self(const bf16* __restrict__ sb, float* __restrict__ ws){
    __shared__ float h[PD];
    __shared__ float stat[2];
    int r=blockIdx.x, t=threadIdx.x;
    int F=ws[O_FLAG]>0.5f;
    const float* w1=ws+O_WPS1;
    float acc=0.f;
    for(int q=0;q<8;q++) acc+=LDI(sb,(size_t)r*8+q,F)*w1[q*PD+t];
    acc=fmaxf(acc+ws[O_BPS1+t],0.f);
    h[t]=acc; __syncthreads();
    if(t==0){
        float sm=0; for(int k=0;k<PD;k++) sm+=h[k];
        float mean=sm/PD;
        float v=0; for(int k=0;k<PD;k++){float d=h[k]-mean; v+=d*d;}
        stat[0]=mean; stat[1]=rsqrtf(v/PD+1e-5f);
    }
    __syncthreads();
    float hn=(acc-stat[0])*stat[1]*ws[O_GPS+t]+ws[O_EPS+t];
    h[t]=hn; __syncthreads();
    float a2=0.f;
    const float* w2=ws+O_WPS2;
    for(int k=0;k<PD;k++) a2+=h[k]*w2[k*PD+t];
    ws[O_PS+(size_t)r*PD+t]=fmaxf(a2+ws[O_BPS2+t],0.f)*ws[O_MF+r];
}

// ---------------- k_pair: wave-parallel pair loop ----------------
// rfw2 staged bf16 (feat/smooth path only — proven safe R19/R20); logit path all-f32.
#define LW1  0          // 512  (w1 8x64)
#define LB1  512        // 64
#define LG_  576        // 64
#define LBE  640        // 64
#define LW2  704        // 4096 (w2 64x64)
#define LB2  4800       // 64
#define LRST 4864       // 64  (rs_w[512:576])
#define LRFB 4928       // 80  (rf_b)
#define LTOT 5008       // f32 words (19.6 KB)
#define NRF  5120       // bf16 rfw2 table (10 KB)

__global__ void __launch_bounds__(256,2) k_pair(const bf16* __restrict__ bbox,
                                                float* __restrict__ ws){
    __shared__ float L[LTOT];
    __shared__ bf16 Lrf[NRF];
    __shared__ float mrg[8];         // per-wave m,l
    __shared__ float macc[4*FF];     // per-wave acc
    int t=threadIdx.x;
    int wv=t>>6, ln=t&63;
    int r=blockIdx.x;
    int b=r/NN, i=r%NN;
    int F=ws[O_FLAG]>0.5f;
    for(int idx=t; idx<LTOT; idx+=256){
        float v;
        if(idx<LB1)       v=ws[O_WPR1+idx];
        else if(idx<LG_)  v=ws[O_BPR1+idx-LB1];
        else if(idx<LBE)  v=ws[O_GPR+idx-LG_];
        else if(idx<LW2)  v=ws[O_EPR+idx-LBE];
        else if(idx<LB2)  v=ws[O_WPR2+idx-LW2];
        else if(idx<LRST) v=ws[O_BPR2+idx-LB2];
        else if(idx<LRFB) v=ws[O_WRS+512+idx-LRST];
        else              v=ws[O_BRF+idx-LRFB];
        L[idx]=v;
    }
    for(int idx=t; idx<NRF; idx+=256)
        Lrf[idx]=__float2bfloat16(ws[O_WRF+(size_t)512*FF+idx]);
    float mi=ws[O_MF+r];
    float rsbv=ws[O_BRS];
    float ss_r=ws[O_SS+r];
    __syncthreads();
    float m_run=-1e30f, l_run=0.f;
    float acc0=0.f, acc1=0.f;
    int f1=64+(ln&15);
    for(int j=wv; j<NN; j+=4){
        float mj=ws[O_MF+b*NN+j];
        float prv;
        if(j==i){
            prv=ws[O_PS+(size_t)r*PD+ln];
        } else {
            size_t bbase=((size_t)r*NN+j)*8;
            float a=0.f;
            #pragma unroll
            for(int q=0;q<8;q++) a+=LDI(bbox,bbase+q,F)*L[LW1+q*PD+ln];
            float h1=fmaxf(a+L[LB1+ln],0.f);
            float sm=h1;
            for(int m=32;m>0;m>>=1) sm+=__shfl_xor(sm,m,64);
            float mean=sm*(1.f/64.f);
            float d=h1-mean;
            float vv=d*d;
            for(int m=32;m>0;m>>=1) vv+=__shfl_xor(vv,m,64);
            float rstd=rsqrtf(vv*(1.f/64.f)+1e-5f);
            float lnv=d*rstd*L[LG_+ln]+L[LBE+ln];
            float a2=0.f;
            for(int k=0;k<PD;k++) a2+=__shfl(lnv,k,64)*L[LW2+k*PD+ln];
            prv=fmaxf(a2+L[LB2+ln],0.f)*mi*mj;
        }
        float lp=prv*L[LRST+ln];
        for(int m=32;m>0;m>>=1) lp+=__shfl_xor(lp,m,64);
        float base=(j==i)? ss_r : ws[O_SO+b*NN+j];
        float lgj=mi*base+lp+rsbv;
        if(ln==0) ws[O_AH+(size_t)r*NN+j]=((j==i)||(lgj>0.f&&mi>0.5f&&mj>0.5f))?1.f:0.f;
        float lgm=(mi>0.5f&&mj>0.5f)? lgj : -1e9f;
        float mnew=fmaxf(m_run,lgm);
        float scl=__expf(m_run-mnew);
        float wj=__expf(lgm-mnew);
        l_run=l_run*scl+wj; m_run=mnew;
        float fp0=0.f, fp1=0.f;
        for(int k=0;k<PD;k++){
            float pk=__shfl(prv,k,64);
            fp0+=pk*b2f(Lrf[k*FF+ln]);
            fp1+=pk*b2f(Lrf[k*FF+f1]);
        }
        float fb0=(j==i)? ws[O_FS+(size_t)r*FF+ln] : ws[O_FO+(size_t)(b*NN+j)*FF+ln];
        float fd0=fmaxf(mi*fb0+fp0+L[LRFB+ln],0.f);
        acc0=acc0*scl+wj*fd0;
        if(ln<16){
            float fb1=(j==i)? ws[O_FS+(size_t)r*FF+f1] : ws[O_FO+(size_t)(b*NN+j)*FF+f1];
            float fd1=fmaxf(mi*fb1+fp1+L[LRFB+f1],0.f);
            acc1=acc1*scl+wj*fd1;
        }
    }
    if(ln==0){ mrg[wv]=m_run; mrg[4+wv]=l_run; }
    macc[wv*FF+ln]=acc0;
    if(ln<16) macc[wv*FF+64+ln]=acc1;
    __syncthreads();
    if(t<FF){
        float mstar=fmaxf(fmaxf(mrg[0],mrg[1]),fmaxf(mrg[2],mrg[3]));
        float lstar=0.f, num=0.f;
        #pragma unroll
        for(int w=0;w<4;w++){
            float e=__expf(mrg[w]-mstar);
            lstar+=mrg[4+w]*e;
            num+=macc[w*FF+t]*e;
        }
        ws[O_RL+(size_t)r*FF+t]=num/lstar*mi;
    }
}

// ---------------- k_adj ----------------
__global__ void k_adj(float* __restrict__ ws){
    __shared__ float Af[NN*NN];
    __shared__ float dinv[NN];
    int b=blockIdx.x, t=threadIdx.x;
    for(int idx=t; idx<NN*NN; idx+=256) Af[idx]=(ws[O_AH+(size_t)b*NN*NN+idx]>0.5f)?1.f:0.f;
    __syncthreads();
    if(t<NN){
        float dg=0.f;
        for(int i=0;i<NN;i++) dg+=Af[i*NN+t];
        dinv[t]=rsqrtf(dg);
    }
    __syncthreads();
    for(int idx=t; idx<NN*NN; idx+=256){
        int i=idx/NN, j=idx%NN;
        ws[O_AN+(size_t)b*NN*NN+idx]=Af[idx]*dinv[i]*dinv[j];
    }
}

// ---------------- kt: T = X @ W (10-row x 256-col register tiles) ----------------
__global__ void kt(int mode, const float* __restrict__ out, const float* __restrict__ ws,
                   const float* __restrict__ W, float* __restrict__ T,
                   int K, int NCOL, int NTILE){
    __shared__ float xs[10*GG];
    int blk=blockIdx.x, t=threadIdx.x;
    int rg=blk/NTILE, tile=blk%NTILE;
    for(int idx=t; idx<10*K; idx+=256){
        int row=idx/K, k=idx-row*K;
        int gr=rg*10+row;
        float v;
        if(mode==0){
            int bb=gr/NN, ii=gr-bb*NN;
            if(k<DD) v=out[(size_t)(2*bb)*NN*DD+(size_t)ii*DD+k];
            else     v=ws[O_RL+(size_t)gr*FF+(k-DD)];
        } else if(mode==1) v=ws[O_X1+(size_t)gr*GG+k];
        else               v=ws[O_X2+(size_t)gr*DD+k];
        xs[row*K+k]=v;
    }
    __syncthreads();
    int c=tile*256+t;
    if(c>=NCOL) return;
    float acc[10];
    #pragma unroll
    for(int u=0;u<10;u++) acc[u]=0.f;
    for(int k=0;k<K;k++){
        float w=W[(size_t)k*NCOL+c];
        #pragma unroll
        for(int u=0;u<10;u++) acc[u]+=xs[u*K+k]*w;
    }
    int gr0=rg*10;
    #pragma unroll
    for(int u=0;u<10;u++) T[(size_t)(gr0+u)*NCOL+c]=acc[u];
}

// ---------------- ka: aggregation ----------------
__global__ void ka(int mode, float* __restrict__ ws, const float* __restrict__ bias,
                   float* __restrict__ out, int NCOL){
    __shared__ float acol[NN];
    int rj=blockIdx.x, t=threadIdx.x;
    int b=rj/NN, j=rj-b*NN;
    if(t<NN) acol[t]=ws[O_AN+(size_t)b*NN*NN+t*NN+j];
    __syncthreads();
    const float* Tb=ws+O_T+(size_t)b*NN*NCOL;
    for(int c=t;c<NCOL;c+=256){
        float acc=0.f;
        for(int i2=0;i2<NN;i2++) acc+=acol[i2]*Tb[(size_t)i2*NCOL+c];
        float v=fmaxf(acc+bias[c],0.f);
        if(mode==2)      out[(size_t)(2*b+1)*NN*DD+(size_t)j*DD+c]=v;
        else if(mode==1) ws[O_X2+(size_t)rj*DD+c]=v;
        else             ws[O_X1+(size_t)rj*GG+c]=v;
    }
}

extern "C" void kernel_launch(void* const* d_in, const int* in_sizes, int n_in,
                              void* d_out, int out_size, void* d_ws, size_t ws_size,
                              hipStream_t stream) {
    const bf16* images  = (const bf16*)d_in[0];
    const bf16* selfbbox= (const bf16*)d_in[1];
    const bf16* bbox    = (const bf16*)d_in[2];

    float* out=(float*)d_out;
    float* ws =(float*)d_ws;

    k_flag<<<1,64,0,stream>>>(images, ws);
    kw<<<512,256,0,stream>>>((const bf16*)d_in[3],(const bf16*)d_in[4],(const bf16*)d_in[5],
                             (const bf16*)d_in[6],(const bf16*)d_in[7],(const bf16*)d_in[8],
                             (const bf16*)d_in[9],(const bf16*)d_in[10],(const bf16*)d_in[11],
                             (const bf16*)d_in[12],(const bf16*)d_in[13],(const bf16*)d_in[14],
                             (const bf16*)d_in[15],(const bf16*)d_in[16],(const bf16*)d_in[17],
                             (const bf16*)d_in[18],(const bf16*)d_in[19],(const bf16*)d_in[20],
                             (const bf16*)d_in[21],(const bf16*)d_in[22],(const bf16*)d_in[23],
                             (const bf16*)d_in[24],(const bf16*)d_in[25],(const bf16*)d_in[26],
                             (const bf16*)d_in[27],(const bf16*)d_in[28],(const bf16*)d_in[29],
                             (const bf16*)d_in[30],(const bf16*)d_in[31],(const bf16*)d_in[32],
                             ws);
    k_pre<<<BN/4,256,0,stream>>>(images, ws, out);
    k_pos_self<<<BN,PD,0,stream>>>(selfbbox, ws);
    k_pair<<<BN,256,0,stream>>>(bbox, ws);
    k_adj<<<BB,256,0,stream>>>(ws);

    kt<<<160*3,256,0,stream>>>(0, out, ws, ws+O_WG1, ws+O_T, GG, GG, 3);
    ka<<<BN,256,0,stream>>>(0, ws, ws+O_BG1, out, GG);
    kt<<<160*2,256,0,stream>>>(1, out, ws, ws+O_WG2, ws+O_T, GG, DD, 2);
    ka<<<BN,256,0,stream>>>(1, ws, ws+O_BG2, out, DD);
    kt<<<160*2,256,0,stream>>>(2, out, ws, ws+O_WG3, ws+O_T, DD, DD, 2);
    ka<<<BN,256,0,stream>>>(2, ws, ws+O_BG3, out, DD);
}

// Round 23
// 827.956 us; speedup vs baseline: 1.0414x; 1.0004x over previous
//
#include <hip/hip_runtime.h>
#include <hip/hip_bf16.h>

typedef __hip_bfloat16 bf16;

#define BB 32
#define NN 50
#define DIN 2048
#define DD 512
#define PD 64
#define FF 80
#define GG 592
#define BN (BB*NN)      // 1600

// ---------------- ws layout (f32 words) ----------------
#define O_FLAG  0
#define O_MF    16
#define O_SS    1616
#define O_SO    3216
#define O_PS    4816
#define O_FS    107216
#define O_FO    235216
#define O_RL    363216
#define O_LG    491216     // full logits [1600x50] (f32 — edge threshold)
#define O_AN    571216
#define O_T     651216
#define O_X1    1598416
#define O_X2    2545616
#define O_WPRE  3364816
#define O_BPRE  4413392
#define O_GPRE  4413904
#define O_EPRE  4414416
#define O_WSUBJ 4414928
#define O_BSUBJ 4677072
#define O_WOBJ  4677584
#define O_BOBJ  4939728
#define O_WPS1  4940240
#define O_BPS1  4940752
#define O_GPS   4940816
#define O_EPS   4940880
#define O_WPS2  4940944
#define O_BPS2  4945040
#define O_WPR1  4945104
#define O_BPR1  4945616
#define O_GPR   4945680
#define O_EPR   4945744
#define O_WPR2  4945808
#define O_BPR2  4949904
#define O_WRS   4949968
#define O_BRS   4950544
#define O_WRF   4950560
#define O_BRF   4996640
#define O_WG1   4996736
#define O_BG1   5347200
#define O_WG2   5347792
#define O_BG2   5650896
#define O_WG3   5651408
#define O_BG3   5913552
#define O_FT    5914064    // per-pair feat [80000x80] -> end 12,314,064 w = 49.3 MB

__device__ __forceinline__ float b2f(bf16 x){ return __bfloat162float(x); }

// Load logical f32 element i of an input buffer (bf16-pair reconstruction when F=1).
__device__ __forceinline__ float LDI(const bf16* p, size_t i, int f32m){
    if(f32m){
        bf16 a=p[2*i], b=p[2*i+1];
        unsigned short lo,hi;
        __builtin_memcpy(&lo,&a,2); __builtin_memcpy(&hi,&b,2);
        unsigned v=((unsigned)hi<<16)|(unsigned)lo;
        float f; __builtin_memcpy(&f,&v,4);
        return f;
    }
    return __bfloat162float(p[i]);
}

// ---------------- flag ----------------
__global__ void k_flag(const bf16* __restrict__ images, float* __restrict__ ws){
    __shared__ int cnt;
    if(threadIdx.x==0) cnt=0;
    __syncthreads();
    bf16 h=images[2*threadIdx.x];
    unsigned short u; __builtin_memcpy(&u,&h,2);
    unsigned e=(u>>7)&0xFF;
    int sane=((u&0x7FFF)==0 || (e>=0x70&&e<=0x85))?1:0;
    atomicAdd(&cnt,sane);
    __syncthreads();
    if(threadIdx.x==0) ws[O_FLAG]=(cnt<48)?1.f:0.f;
}

// ---------------- kw: convert all weights to f32 in ws (no quantization — R21) ----------------
__device__ __forceinline__ void conv(const bf16* s, float* d, int n, int F, int i0, int st){
    for(int g=i0; g<n; g+=st) d[g]=LDI(s,(size_t)g,F);
}
__global__ void kw(const bf16* p0,const bf16* p1,const bf16* p2,const bf16* p3,
                   const bf16* p4,const bf16* p5,const bf16* p6,const bf16* p7,
                   const bf16* p8,const bf16* p9,const bf16* p10,const bf16* p11,
                   const bf16* p12,const bf16* p13,const bf16* p14,const bf16* p15,
                   const bf16* p16,const bf16* p17,const bf16* p18,const bf16* p19,
                   const bf16* p20,const bf16* p21,const bf16* p22,const bf16* p23,
                   const bf16* p24,const bf16* p25,const bf16* p26,const bf16* p27,
                   const bf16* p28,const bf16* p29, float* __restrict__ ws){
    int F=ws[O_FLAG]>0.5f;
    int i0=blockIdx.x*256+threadIdx.x, st=gridDim.x*256;
    conv(p0, ws+O_WPRE, 1048576,F,i0,st);
    conv(p1, ws+O_BPRE, 512,F,i0,st);
    conv(p2, ws+O_GPRE, 512,F,i0,st);
    conv(p3, ws+O_EPRE, 512,F,i0,st);
    conv(p4, ws+O_WSUBJ,262144,F,i0,st);
    conv(p5, ws+O_BSUBJ,512,F,i0,st);
    conv(p6, ws+O_WOBJ, 262144,F,i0,st);
    conv(p7, ws+O_BOBJ, 512,F,i0,st);
    conv(p8, ws+O_WPS1, 512,F,i0,st);
    conv(p9, ws+O_BPS1, 64,F,i0,st);
    conv(p10,ws+O_GPS,  64,F,i0,st);
    conv(p11,ws+O_EPS,  64,F,i0,st);
    conv(p12,ws+O_WPS2, 4096,F,i0,st);
    conv(p13,ws+O_BPS2, 64,F,i0,st);
    conv(p14,ws+O_WPR1, 512,F,i0,st);
    conv(p15,ws+O_BPR1, 64,F,i0,st);
    conv(p16,ws+O_GPR,  64,F,i0,st);
    conv(p17,ws+O_EPR,  64,F,i0,st);
    conv(p18,ws+O_WPR2, 4096,F,i0,st);
    conv(p19,ws+O_BPR2, 64,F,i0,st);
    conv(p20,ws+O_WRS,  576,F,i0,st);
    conv(p21,ws+O_BRS,  1,F,i0,st);
    conv(p22,ws+O_WRF,  46080,F,i0,st);
    conv(p23,ws+O_BRF,  80,F,i0,st);
    conv(p24,ws+O_WG1,  350464,F,i0,st);
    conv(p25,ws+O_BG1,  592,F,i0,st);
    conv(p26,ws+O_WG2,  303104,F,i0,st);
    conv(p27,ws+O_BG2,  512,F,i0,st);
    conv(p28,ws+O_WG3,  262144,F,i0,st);
    conv(p29,ws+O_BG3,  512,F,i0,st);
}

// ---------------- k_pre: 4 rows/block, 256 threads, unroll-8 register prefetch ----------------
__global__ void __launch_bounds__(256,3) k_pre(const bf16* __restrict__ images,
                                               float* __restrict__ ws,
                                               float* __restrict__ out){
    __shared__ float a[4*DIN];       // 32KB; later reused for xs(4)|xo(4) rows
    __shared__ float xr[4*DD];       // 8KB
    __shared__ float red[256];
    int blk=blockIdx.x, t=threadIdx.x;
    int r0=blk*4;
    int F=ws[O_FLAG]>0.5f;
    const float* wPre=ws+O_WPRE; const float* bPre=ws+O_BPRE;
    const float* gPre=ws+O_GPRE; const float* ePre=ws+O_EPRE;
    const float* wSu=ws+O_WSUBJ; const float* bSu=ws+O_BSUBJ;
    const float* wOb=ws+O_WOBJ;  const float* bOb=ws+O_BOBJ;
    const float* wRs=ws+O_WRS;   const float* wRf=ws+O_WRF;

    float psum[4]={0.f,0.f,0.f,0.f};
    for(int idx=t; idx<4*DIN; idx+=256){
        float v=LDI(images,(size_t)r0*DIN+idx,F);
        a[idx]=v;
        psum[idx>>11]+=v;
    }
    float mrow[4];
    for(int row=0;row<4;row++){
        red[t]=psum[row]; __syncthreads();
        for(int o=128;o>0;o>>=1){ if(t<o) red[t]+=red[t+o]; __syncthreads(); }
        mrow[row]=(red[0]!=0.f)?1.f:0.f;
        __syncthreads();
    }
    if(t<4){
        ws[O_MF+r0+t]=mrow[t];
        out[(size_t)BB*2*NN*DD + r0 + t]=1.f-mrow[t];
    }
    int c0=t, c1=t+256;
    float acc[4][2]={};
    for(int k0=0;k0<DIN;k0+=8){
        float w0v[8], w1v[8];
        #pragma unroll
        for(int u=0;u<8;u++){
            w0v[u]=wPre[(size_t)(k0+u)*DD+c0];
            w1v[u]=wPre[(size_t)(k0+u)*DD+c1];
        }
        #pragma unroll
        for(int u=0;u<8;u++){
            #pragma unroll
            for(int row=0;row<4;row++){
                float v=a[row*DIN+k0+u];
                acc[row][0]+=v*w0v[u]; acc[row][1]+=v*w1v[u];
            }
        }
    }
    float y[4][2];
    #pragma unroll
    for(int row=0;row<4;row++){
        y[row][0]=fmaxf(acc[row][0]+bPre[c0],0.f);
        y[row][1]=fmaxf(acc[row][1]+bPre[c1],0.f);
    }
    for(int row=0;row<4;row++){
        __syncthreads();
        red[t]=y[row][0]+y[row][1]; __syncthreads();
        for(int o=128;o>0;o>>=1){ if(t<o) red[t]+=red[t+o]; __syncthreads(); }
        float mean=red[0]/DD;
        __syncthreads();
        float d0=y[row][0]-mean, d1=y[row][1]-mean;
        red[t]=d0*d0+d1*d1; __syncthreads();
        for(int o=128;o>0;o>>=1){ if(t<o) red[t]+=red[t+o]; __syncthreads(); }
        float rstd=rsqrtf(red[0]/DD+1e-5f);
        float xv0=d0*rstd*gPre[c0]+ePre[c0];
        float xv1=d1*rstd*gPre[c1]+ePre[c1];
        xr[row*DD+c0]=xv0; xr[row*DD+c1]=xv1;
        int r=r0+row;
        size_t ob=((size_t)(r/NN)*2)*NN*DD+(size_t)(r%NN)*DD;
        out[ob+c0]=xv0; out[ob+c1]=xv1;
    }
    __syncthreads();
    float su[4][2]={}, oo[4][2]={};
    for(int k0=0;k0<DD;k0+=8){
        float ws0v[8], ws1v[8], wo0v[8], wo1v[8];
        #pragma unroll
        for(int u=0;u<8;u++){
            ws0v[u]=wSu[(size_t)(k0+u)*DD+c0]; ws1v[u]=wSu[(size_t)(k0+u)*DD+c1];
            wo0v[u]=wOb[(size_t)(k0+u)*DD+c0]; wo1v[u]=wOb[(size_t)(k0+u)*DD+c1];
        }
        #pragma unroll
        for(int u=0;u<8;u++){
            #pragma unroll
            for(int row=0;row<4;row++){
                float v=xr[row*DD+k0+u];
                su[row][0]+=v*ws0v[u]; su[row][1]+=v*ws1v[u];
                oo[row][0]+=v*wo0v[u]; oo[row][1]+=v*wo1v[u];
            }
        }
    }
    __syncthreads();
    #pragma unroll
    for(int row=0;row<4;row++){
        a[row*DD+c0]     =fmaxf(su[row][0]+bSu[c0],0.f)*mrow[row];
        a[row*DD+c1]     =fmaxf(su[row][1]+bSu[c1],0.f)*mrow[row];
        a[4*DD+row*DD+c0]=fmaxf(oo[row][0]+bOb[c0],0.f)*mrow[row];
        a[4*DD+row*DD+c1]=fmaxf(oo[row][1]+bOb[c1],0.f)*mrow[row];
    }
    __syncthreads();
    int wv=t>>6, ln=t&63;
    float ps=0.f, po=0.f;
    for(int k=ln;k<DD;k+=64){ ps+=a[wv*DD+k]*wRs[k]; po+=a[4*DD+wv*DD+k]*wRs[k]; }
    for(int m=32;m>0;m>>=1){ ps+=__shfl_xor(ps,m,64); po+=__shfl_xor(po,m,64); }
    if(ln==0){ ws[O_SS+r0+wv]=ps; ws[O_SO+r0+wv]=po; }
    for(int pass=0;pass<3;pass++){
        int cb=pass*3+(t/80);
        if(t<240 && cb<8){
            int row=cb>>1, sel=cb&1;
            int f=t%80;
            const float* xv=a + sel*4*DD + row*DD;
            float accf=0.f;
            for(int k=0;k<DD;k++) accf+=xv[k]*wRf[(size_t)k*FF+f];
            ws[(sel? O_FO:O_FS)+(size_t)(r0+row)*FF+f]=accf;
        }
    }
}

// ---------------- k_pos_self ----------------
__global__ void k_pos_self(const bf16* __restrict__ sb, float* __restrict__ ws){
    __shared__ float h[PD];
    __shared__ float stat[2];
    int r=blockIdx.x, t=threadIdx.x;
    int F=ws[O_FLAG]>0.5f;
    const float* w1=ws+O_WPS1;
    float acc=0.f;
    for(int q=0;q<8;q++) acc+=LDI(sb,(size_t)r*8+q,F)*w1[q*PD+t];
    acc=fmaxf(acc+ws[O_BPS1+t],0.f);
    h[t]=acc; __syncthreads();
    if(t==0){
        float sm=0; for(int k=0;k<PD;k++) sm+=h[k];
        float mean=sm/PD;
        float v=0; for(int k=0;k<PD;k++){float d=h[k]-mean; v+=d*d;}
        stat[0]=mean; stat[1]=rsqrtf(v/PD+1e-5f);
    }
    __syncthreads();
    float hn=(acc-stat[0])*stat[1]*ws[O_GPS+t]+ws[O_EPS+t];
    h[t]=hn; __syncthreads();
    float a2=0.f;
    const float* w2=ws+O_WPS2;
    for(int k=0;k<PD;k++) a2+=h[k]*w2[k*PD+t];
    ws[O_PS+(size_t)r*PD+t]=fmaxf(a2+ws[O_BPS2+t],0.f)*ws[O_MF+r];
}

// ---------------- k_pairp: one wave per PAIR (no j-loop) ----------------
// Writes lg[r][j] (f32) and ft[p][0:80] (f32). rfw2 staged bf16 (feat path only).
#define LW1  0          // 512
#define LB1  512        // 64
#define LG_  576        // 64
#define LBE  640        // 64
#define LW2  704        // 4096
#define LB2  4800       // 64
#define LRST 4864       // 64
#define LRFB 4928       // 80
#define LTOT 5008       // f32 words
#define NRF  5120       // bf16 rfw2 table

__global__ void __launch_bounds__(256,2) k_pairp(const bf16* __restrict__ bbox,
                                                 float* __restrict__ ws){
    __shared__ float L[LTOT];
    __shared__ bf16 Lrf[NRF];
    int t=threadIdx.x;
    int wv=t>>6, ln=t&63;
    int p=blockIdx.x*4+wv;          // pair index, grid=20000 -> p<80000 exactly
    int r=p/NN, j=p-r*NN;
    int b=r/NN, i=r-b*NN;
    int F=ws[O_FLAG]>0.5f;
    for(int idx=t; idx<LTOT; idx+=256){
        float v;
        if(idx<LB1)       v=ws[O_WPR1+idx];
        else if(idx<LG_)  v=ws[O_BPR1+idx-LB1];
        else if(idx<LBE)  v=ws[O_GPR+idx-LG_];
        else if(idx<LW2)  v=ws[O_EPR+idx-LBE];
        else if(idx<LB2)  v=ws[O_WPR2+idx-LW2];
        else if(idx<LRST) v=ws[O_BPR2+idx-LB2];
        else if(idx<LRFB) v=ws[O_WRS+512+idx-LRST];
        else              v=ws[O_BRF+idx-LRFB];
        L[idx]=v;
    }
    for(int idx=t; idx<NRF; idx+=256)
        Lrf[idx]=__float2bfloat16(ws[O_WRF+(size_t)512*FF+idx]);
    float mi=ws[O_MF+r];
    float mj=ws[O_MF+b*NN+j];
    float rsbv=ws[O_BRS];
    __syncthreads();
    float prv;
    if(j==i){
        prv=ws[O_PS+(size_t)r*PD+ln];
    } else {
        size_t bbase=((size_t)r*NN+j)*8;
        float a=0.f;
        #pragma unroll
        for(int q=0;q<8;q++) a+=LDI(bbox,bbase+q,F)*L[LW1+q*PD+ln];
        float h1=fmaxf(a+L[LB1+ln],0.f);
        float sm=h1;
        for(int m=32;m>0;m>>=1) sm+=__shfl_xor(sm,m,64);
        float mean=sm*(1.f/64.f);
        float d=h1-mean;
        float vv=d*d;
        for(int m=32;m>0;m>>=1) vv+=__shfl_xor(vv,m,64);
        float rstd=rsqrtf(vv*(1.f/64.f)+1e-5f);
        float lnv=d*rstd*L[LG_+ln]+L[LBE+ln];
        float a2=0.f;
        for(int k=0;k<PD;k++) a2+=__shfl(lnv,k,64)*L[LW2+k*PD+ln];
        prv=fmaxf(a2+L[LB2+ln],0.f)*mi*mj;
    }
    // logit (all f32)
    float lp=prv*L[LRST+ln];
    for(int m=32;m>0;m>>=1) lp+=__shfl_xor(lp,m,64);
    float base=(j==i)? ws[O_SS+r] : ws[O_SO+b*NN+j];
    float lgj=mi*base+lp+rsbv;
    if(ln==0) ws[O_LG+(size_t)r*NN+j]=lgj;
    // feat
    int f1=64+(ln&15);
    float fp0=0.f, fp1=0.f;
    for(int k=0;k<PD;k++){
        float pk=__shfl(prv,k,64);
        fp0+=pk*b2f(Lrf[k*FF+ln]);
        fp1+=pk*b2f(Lrf[k*FF+f1]);
    }
    float fb0=(j==i)? ws[O_FS+(size_t)r*FF+ln] : ws[O_FO+(size_t)(b*NN+j)*FF+ln];
    ws[O_FT+(size_t)p*FF+ln]=fmaxf(mi*fb0+fp0+L[LRFB+ln],0.f);
    if(ln<16){
        float fb1=(j==i)? ws[O_FS+(size_t)r*FF+f1] : ws[O_FO+(size_t)(b*NN+j)*FF+f1];
        ws[O_FT+(size_t)p*FF+f1]=fmaxf(mi*fb1+fp1+L[LRFB+f1],0.f);
    }
}

// ---------------- k_relas: exact masked softmax + feat pooling ----------------
__global__ void k_relas(float* __restrict__ ws){
    __shared__ float attn[NN];
    int r=blockIdx.x, t=threadIdx.x;
    int b=r/NN;
    float mi=ws[O_MF+r];
    if(t<NN){
        float mj=ws[O_MF+b*NN+t];
        bool pm=(mi>0.5f)&&(mj>0.5f);
        attn[t]=pm? ws[O_LG+(size_t)r*NN+t] : -1e9f;
    }
    __syncthreads();
    if(t==0){
        float mx=-1e30f;
        for(int j=0;j<NN;j++) mx=fmaxf(mx,attn[j]);
        float sm=0.f;
        for(int j=0;j<NN;j++){ float e=__expf(attn[j]-mx); attn[j]=e; sm+=e; }
        float inv=1.f/sm;
        for(int j=0;j<NN;j++) attn[j]*=inv;
    }
    __syncthreads();
    if(t<FF){
        float s=0.f;
        const float* ft=ws+O_FT+(size_t)r*NN*FF;
        for(int j=0;j<NN;j++) s+=attn[j]*ft[(size_t)j*FF+t];
        ws[O_RL+(size_t)r*FF+t]=s*mi;
    }
}

// ---------------- k_adj: Af from logits + mf ----------------
__global__ void k_adj(float* __restrict__ ws){
    __shared__ float Af[NN*NN];
    __shared__ float dinv[NN];
    int b=blockIdx.x, t=threadIdx.x;
    for(int idx=t; idx<NN*NN; idx+=256){
        int i=idx/NN, j=idx%NN;
        float l=ws[O_LG+(size_t)b*NN*NN+idx];
        bool a=(l>0.f)&&(ws[O_MF+b*NN+i]>0.5f)&&(ws[O_MF+b*NN+j]>0.5f);
        Af[idx]=(a||i==j)?1.f:0.f;
    }
    __syncthreads();
    if(t<NN){
        float dg=0.f;
        for(int i=0;i<NN;i++) dg+=Af[i*NN+t];
        dinv[t]=rsqrtf(dg);
    }
    __syncthreads();
    for(int idx=t; idx<NN*NN; idx+=256){
        int i=idx/NN, j=idx%NN;
        ws[O_AN+(size_t)b*NN*NN+idx]=Af[idx]*dinv[i]*dinv[j];
    }
}

// ---------------- kt: T = X @ W (10-row x 256-col register tiles) ----------------
__global__ void kt(int mode, const float* __restrict__ out, const float* __restrict__ ws,
                   const float* __restrict__ W, float* __restrict__ T,
                   int K, int NCOL, int NTILE){
    __shared__ float xs[10*GG];
    int blk=blockIdx.x, t=threadIdx.x;
    int rg=blk/NTILE, tile=blk%NTILE;
    for(int idx=t; idx<10*K; idx+=256){
        int row=idx/K, k=idx-row*K;
        int gr=rg*10+row;
        float v;
        if(mode==0){
            int bb=gr/NN, ii=gr-bb*NN;
            if(k<DD) v=out[(size_t)(2*bb)*NN*DD+(size_t)ii*DD+k];
            else     v=ws[O_RL+(size_t)gr*FF+(k-DD)];
        } else if(mode==1) v=ws[O_X1+(size_t)gr*GG+k];
        else               v=ws[O_X2+(size_t)gr*DD+k];
        xs[row*K+k]=v;
    }
    __syncthreads();
    int c=tile*256+t;
    if(c>=NCOL) return;
    float acc[10];
    #pragma unroll
    for(int u=0;u<10;u++) acc[u]=0.f;
    for(int k=0;k<K;k++){
        float w=W[(size_t)k*NCOL+c];
        #pragma unroll
        for(int u=0;u<10;u++) acc[u]+=xs[u*K+k]*w;
    }
    int gr0=rg*10;
    #pragma unroll
    for(int u=0;u<10;u++) T[(size_t)(gr0+u)*NCOL+c]=acc[u];
}

// ---------------- ka: aggregation ----------------
__global__ void ka(int mode, float* __restrict__ ws, const float* __restrict__ bias,
                   float* __restrict__ out, int NCOL){
    __shared__ float acol[NN];
    int rj=blockIdx.x, t=threadIdx.x;
    int b=rj/NN, j=rj-b*NN;
    if(t<NN) acol[t]=ws[O_AN+(size_t)b*NN*NN+t*NN+j];
    __syncthreads();
    const float* Tb=ws+O_T+(size_t)b*NN*NCOL;
    for(int c=t;c<NCOL;c+=256){
        float acc=0.f;
        for(int i2=0;i2<NN;i2++) acc+=acol[i2]*Tb[(size_t)i2*NCOL+c];
        float v=fmaxf(acc+bias[c],0.f);
        if(mode==2)      out[(size_t)(2*b+1)*NN*DD+(size_t)j*DD+c]=v;
        else if(mode==1) ws[O_X2+(size_t)rj*DD+c]=v;
        else             ws[O_X1+(size_t)rj*GG+c]=v;
    }
}

extern "C" void kernel_launch(void* const* d_in, const int* in_sizes, int n_in,
                              void* d_out, int out_size, void* d_ws, size_t ws_size,
                              hipStream_t stream) {
    const bf16* images  = (const bf16*)d_in[0];
    const bf16* selfbbox= (const bf16*)d_in[1];
    const bf16* bbox    = (const bf16*)d_in[2];

    float* out=(float*)d_out;
    float* ws =(float*)d_ws;

    k_flag<<<1,64,0,stream>>>(images, ws);
    kw<<<512,256,0,stream>>>((const bf16*)d_in[3],(const bf16*)d_in[4],(const bf16*)d_in[5],
                             (const bf16*)d_in[6],(const bf16*)d_in[7],(const bf16*)d_in[8],
                             (const bf16*)d_in[9],(const bf16*)d_in[10],(const bf16*)d_in[11],
                             (const bf16*)d_in[12],(const bf16*)d_in[13],(const bf16*)d_in[14],
                             (const bf16*)d_in[15],(const bf16*)d_in[16],(const bf16*)d_in[17],
                             (const bf16*)d_in[18],(const bf16*)d_in[19],(const bf16*)d_in[20],
                             (const bf16*)d_in[21],(const bf16*)d_in[22],(const bf16*)d_in[23],
                             (const bf16*)d_in[24],(const bf16*)d_in[25],(const bf16*)d_in[26],
                             (const bf16*)d_in[27],(const bf16*)d_in[28],(const bf16*)d_in[29],
                             (const bf16*)d_in[30],(const bf16*)d_in[31],(const bf16*)d_in[32],
                             ws);
    k_pre<<<BN/4,256,0,stream>>>(images, ws, out);
    k_pos_self<<<BN,PD,0,stream>>>(selfbbox, ws);
    k_pairp<<<20000,256,0,stream>>>(bbox, ws);
    k_relas<<<BN,128,0,stream>>>(ws);
    k_adj<<<BB,256,0,stream>>>(ws);

    kt<<<160*3,256,0,stream>>>(0, out, ws, ws+O_WG1, ws+O_T, GG, GG, 3);
    ka<<<BN,256,0,stream>>>(0, ws, ws+O_BG1, out, GG);
    kt<<<160*2,256,0,stream>>>(1, out, ws, ws+O_WG2, ws+O_T, GG, DD, 2);
    ka<<<BN,256,0,stream>>>(1, ws, ws+O_BG2, out, DD);
    kt<<<160*2,256,0,stream>>>(2, out, ws, ws+O_WG3, ws+O_T, DD, DD, 2);
    ka<<<BN,256,0,stream>>>(2, ws, ws+O_BG3, out, DD);
}